// Round 1
// baseline (4318.012 us; speedup 1.0000x reference)
//
#include <hip/hip_runtime.h>

constexpr int IN_DIM = 128;

// ---------- degree / normalization ----------
__global__ void init_deg_k(float* deg, int n) {
  int i = blockIdx.x * blockDim.x + threadIdx.x;
  if (i < n) deg[i] = 1.0f;  // self-loop
}

__global__ void count_deg_k(const int* __restrict__ ei, int E, float* __restrict__ deg) {
  int i = blockIdx.x * blockDim.x + threadIdx.x;
  int stride = gridDim.x * blockDim.x;
  for (; i < E; i += stride) {
    int d = ei[E + i];  // dst
    unsafeAtomicAdd(&deg[d], 1.0f);
  }
}

__global__ void dinv_k(float* deg, int n) {
  int i = blockIdx.x * blockDim.x + threadIdx.x;
  if (i < n) deg[i] = rsqrtf(deg[i]);  // deg >= 1 always (self-loop)
}

// ---------- matmul with dinv row-scale epilogue ----------
// HS[row][col0+o] = dinv[row] * sum_k X[row][k] * W[k][col0+o]
// Each block: 64 output columns (blockIdx.y), 16 rows per pass.
template<int OUT>
__global__ __launch_bounds__(256)
void matmul_scale_k(const float* __restrict__ X, const float* __restrict__ W,
                    const float* __restrict__ dinv, float* __restrict__ HS, int n) {
  constexpr int COLS = 64;
  constexpr int OG = COLS / 4;     // 16 threads per row
  constexpr int RPP = 256 / OG;    // 16 rows per pass
  __shared__ float Ws[IN_DIM * COLS];  // 32 KB
  __shared__ float XS[RPP * IN_DIM];   // 8 KB
  const int col0 = blockIdx.y * COLS;

  for (int i = threadIdx.x; i < IN_DIM * COLS; i += 256) {
    int k = i / COLS, c = i % COLS;
    Ws[i] = W[k * OUT + col0 + c];
  }

  const int og = threadIdx.x % OG;
  const int r  = threadIdx.x / OG;
  const int o4 = og * 4;

  for (int row0 = blockIdx.x * RPP; row0 < n; row0 += gridDim.x * RPP) {
    __syncthreads();  // also covers initial Ws staging
    for (int i = threadIdx.x; i < RPP * IN_DIM; i += 256) {
      int row = row0 + (i / IN_DIM);
      XS[i] = (row < n) ? X[(long long)row * IN_DIM + (i % IN_DIM)] : 0.0f;
    }
    __syncthreads();

    float4 acc = make_float4(0.f, 0.f, 0.f, 0.f);
#pragma unroll
    for (int k = 0; k < IN_DIM; k += 4) {
      float4 xv = *(const float4*)&XS[r * IN_DIM + k];
      const float* wp = &Ws[k * COLS + o4];
      float4 w0 = *(const float4*)(wp);
      float4 w1 = *(const float4*)(wp + COLS);
      float4 w2 = *(const float4*)(wp + 2 * COLS);
      float4 w3 = *(const float4*)(wp + 3 * COLS);
      acc.x = fmaf(xv.x, w0.x, fmaf(xv.y, w1.x, fmaf(xv.z, w2.x, fmaf(xv.w, w3.x, acc.x))));
      acc.y = fmaf(xv.x, w0.y, fmaf(xv.y, w1.y, fmaf(xv.z, w2.y, fmaf(xv.w, w3.y, acc.y))));
      acc.z = fmaf(xv.x, w0.z, fmaf(xv.y, w1.z, fmaf(xv.z, w2.z, fmaf(xv.w, w3.z, acc.z))));
      acc.w = fmaf(xv.x, w0.w, fmaf(xv.y, w1.w, fmaf(xv.z, w2.w, fmaf(xv.w, w3.w, acc.w))));
    }
    int row = row0 + r;
    if (row < n) {
      float s = dinv[row];
      *(float4*)&HS[(long long)row * OUT + col0 + o4] =
          make_float4(acc.x * s, acc.y * s, acc.z * s, acc.w * s);
    }
  }
}

// ---------- edge scatter: AGG[dst] += HS[src] ----------
template<int OUT>
__global__ __launch_bounds__(256)
void scatter_k(const int* __restrict__ ei, int E, const float* __restrict__ HS,
               float* __restrict__ AGG) {
  constexpr int TPE = OUT / 4;  // threads per edge (float4 each)
  long long t = (long long)blockIdx.x * blockDim.x + threadIdx.x;
  const int lo = (int)(t % TPE) * 4;
  long long e = t / TPE;
  const long long estep = (long long)gridDim.x * blockDim.x / TPE;
  for (; e < E; e += estep) {
    int s = ei[e];
    int d = ei[E + e];
    float4 v = *(const float4*)&HS[(long long)s * OUT + lo];
    float* dst = &AGG[(long long)d * OUT + lo];
    unsafeAtomicAdd(dst + 0, v.x);
    unsafeAtomicAdd(dst + 1, v.y);
    unsafeAtomicAdd(dst + 2, v.z);
    unsafeAtomicAdd(dst + 3, v.w);
  }
}

// ---------- Y = relu(dinv*(AGG + HS) + bias) ----------
template<int OUT>
__global__ __launch_bounds__(256)
void finalize_k(const float* AGG, const float* __restrict__ HS,
                const float* __restrict__ dinv, const float* __restrict__ bias,
                float* Y, int n) {
  long long total = (long long)n * (OUT / 4);
  for (long long i = (long long)blockIdx.x * blockDim.x + threadIdx.x; i < total;
       i += (long long)gridDim.x * blockDim.x) {
    long long base = i * 4;
    int row = (int)(base / OUT);
    int col = (int)(base % OUT);
    float di = dinv[row];
    float4 a = ((const float4*)AGG)[i];
    float4 h = ((const float4*)HS)[i];
    float4 bb = *(const float4*)&bias[col];
    float4 y;
    y.x = fmaxf(fmaf(di, a.x + h.x, bb.x), 0.f);
    y.y = fmaxf(fmaf(di, a.y + h.y, bb.y), 0.f);
    y.z = fmaxf(fmaf(di, a.z + h.z, bb.z), 0.f);
    y.w = fmaxf(fmaf(di, a.w + h.w, bb.w), 0.f);
    ((float4*)Y)[i] = y;
  }
}

extern "C" void kernel_launch(void* const* d_in, const int* in_sizes, int n_in,
                              void* d_out, int out_size, void* d_ws, size_t ws_size,
                              hipStream_t stream) {
  const float* x  = (const float*)d_in[0];
  const int*   ei = (const int*)d_in[1];   // edge_index (JAX downcasts int64->int32)
  const float* W1 = (const float*)d_in[2];
  const float* b1 = (const float*)d_in[3];
  const float* W2 = (const float*)d_in[4];
  const float* b2 = (const float*)d_in[5];
  float* out = (float*)d_out;

  const int n = in_sizes[0] / IN_DIM;   // 100000
  const int E = in_sizes[1] / 2;        // 1600000

  // workspace layout
  char* ws = (char*)d_ws;
  float* dinv = (float*)ws;                                   // n floats
  float* A    = (float*)(ws + (512 << 10));                   // 51.2 MB: hs1, then hs2+agg2
  float* B    = (float*)(ws + (512 << 10) + (size_t)n * 128 * 4);  // 51.2 MB: agg1 -> x1
  float* hs2  = A;
  float* agg2 = A + (size_t)n * 64;

  const int nb = (n + 255) / 256;

  // normalization coefficients
  init_deg_k<<<nb, 256, 0, stream>>>(dinv, n);
  count_deg_k<<<2048, 256, 0, stream>>>(ei, E, dinv);
  dinv_k<<<nb, 256, 0, stream>>>(dinv, n);

  // ----- layer 1 (128 -> 128) -----
  matmul_scale_k<128><<<dim3(1024, 2), 256, 0, stream>>>(x, W1, dinv, A, n);
  hipMemsetAsync(B, 0, (size_t)n * 128 * 4, stream);
  scatter_k<128><<<8192, 256, 0, stream>>>(ei, E, A, B);
  finalize_k<128><<<2048, 256, 0, stream>>>(B, A, dinv, b1, B, n);  // x1 in place

  // ----- layer 2 (128 -> 64) -----
  matmul_scale_k<64><<<dim3(1024, 1), 256, 0, stream>>>(B, W2, dinv, hs2, n);
  hipMemsetAsync(agg2, 0, (size_t)n * 64 * 4, stream);
  scatter_k<64><<<8192, 256, 0, stream>>>(ei, E, hs2, agg2);
  finalize_k<64><<<2048, 256, 0, stream>>>(agg2, hs2, dinv, b2, out, n);
}

// Round 2
// 729.362 us; speedup vs baseline: 5.9203x; 5.9203x over previous
//
#include <hip/hip_runtime.h>

constexpr int IN_DIM = 128;

// ---------- degree histogram (edges only; self-loop added analytically) ----------
__global__ void count_deg_k(const int* __restrict__ ei, int E, int* __restrict__ cnt) {
  int i = blockIdx.x * blockDim.x + threadIdx.x;
  int stride = gridDim.x * blockDim.x;
  for (; i < E; i += stride) {
    atomicAdd(&cnt[ei[E + i]], 1);
  }
}

__global__ void dinv_k(const int* __restrict__ cnt, float* __restrict__ dinv, int n) {
  int i = blockIdx.x * blockDim.x + threadIdx.x;
  if (i < n) dinv[i] = rsqrtf((float)cnt[i] + 1.0f);  // +1 self-loop
}

// ---------- single-workgroup exclusive scan: cnt -> off (n+1), cursor ----------
__global__ __launch_bounds__(1024)
void scan_k(const int* __restrict__ cnt, int* __restrict__ off,
            int* __restrict__ cursor, int n) {
  __shared__ int sdata[1024];
  __shared__ int carry;
  if (threadIdx.x == 0) carry = 0;
  __syncthreads();
  for (int base = 0; base < n; base += 1024) {
    int i = base + threadIdx.x;
    int v = (i < n) ? cnt[i] : 0;
    int c = carry;
    sdata[threadIdx.x] = v;
    __syncthreads();
#pragma unroll
    for (int ofs = 1; ofs < 1024; ofs <<= 1) {
      int t = (threadIdx.x >= ofs) ? sdata[threadIdx.x - ofs] : 0;
      __syncthreads();
      sdata[threadIdx.x] += t;
      __syncthreads();
    }
    int incl = sdata[threadIdx.x];
    int excl = c + incl - v;
    if (i < n) { off[i] = excl; cursor[i] = excl; }
    __syncthreads();
    if (threadIdx.x == 1023) carry = c + incl;
    __syncthreads();
  }
  if (threadIdx.x == 0) off[n] = carry;  // == E
}

// ---------- scatter edges into CSR: sorted_src grouped by dst ----------
__global__ void fill_csr_k(const int* __restrict__ ei, int E,
                           int* __restrict__ cursor, int* __restrict__ ssrc) {
  int i = blockIdx.x * blockDim.x + threadIdx.x;
  int stride = gridDim.x * blockDim.x;
  for (; i < E; i += stride) {
    int s = ei[i];
    int d = ei[E + i];
    int pos = atomicAdd(&cursor[d], 1);
    ssrc[pos] = s;
  }
}

// ---------- matmul with dinv row-scale epilogue ----------
// HS[row][col0+o] = dinv[row] * sum_k X[row][k] * W[k][col0+o]
template<int OUT>
__global__ __launch_bounds__(256)
void matmul_scale_k(const float* __restrict__ X, const float* __restrict__ W,
                    const float* __restrict__ dinv, float* __restrict__ HS, int n) {
  constexpr int COLS = 64;
  constexpr int OG = COLS / 4;     // 16 threads per row
  constexpr int RPP = 256 / OG;    // 16 rows per pass
  __shared__ float Ws[IN_DIM * COLS];  // 32 KB
  __shared__ float XS[RPP * IN_DIM];   // 8 KB
  const int col0 = blockIdx.y * COLS;

  for (int i = threadIdx.x; i < IN_DIM * COLS; i += 256) {
    int k = i / COLS, c = i % COLS;
    Ws[i] = W[k * OUT + col0 + c];
  }

  const int og = threadIdx.x % OG;
  const int r  = threadIdx.x / OG;
  const int o4 = og * 4;

  for (int row0 = blockIdx.x * RPP; row0 < n; row0 += gridDim.x * RPP) {
    __syncthreads();  // also covers initial Ws staging
    for (int i = threadIdx.x; i < RPP * IN_DIM; i += 256) {
      int row = row0 + (i / IN_DIM);
      XS[i] = (row < n) ? X[(long long)row * IN_DIM + (i % IN_DIM)] : 0.0f;
    }
    __syncthreads();

    float4 acc = make_float4(0.f, 0.f, 0.f, 0.f);
#pragma unroll
    for (int k = 0; k < IN_DIM; k += 4) {
      float4 xv = *(const float4*)&XS[r * IN_DIM + k];
      const float* wp = &Ws[k * COLS + o4];
      float4 w0 = *(const float4*)(wp);
      float4 w1 = *(const float4*)(wp + COLS);
      float4 w2 = *(const float4*)(wp + 2 * COLS);
      float4 w3 = *(const float4*)(wp + 3 * COLS);
      acc.x = fmaf(xv.x, w0.x, fmaf(xv.y, w1.x, fmaf(xv.z, w2.x, fmaf(xv.w, w3.x, acc.x))));
      acc.y = fmaf(xv.x, w0.y, fmaf(xv.y, w1.y, fmaf(xv.z, w2.y, fmaf(xv.w, w3.y, acc.y))));
      acc.z = fmaf(xv.x, w0.z, fmaf(xv.y, w1.z, fmaf(xv.z, w2.z, fmaf(xv.w, w3.z, acc.z))));
      acc.w = fmaf(xv.x, w0.w, fmaf(xv.y, w1.w, fmaf(xv.z, w2.w, fmaf(xv.w, w3.w, acc.w))));
    }
    int row = row0 + r;
    if (row < n) {
      float s = dinv[row];
      *(float4*)&HS[(long long)row * OUT + col0 + o4] =
          make_float4(acc.x * s, acc.y * s, acc.z * s, acc.w * s);
    }
  }
}

// ---------- CSR aggregate + fused finalize ----------
// Y[d] = relu(dinv[d] * (HS[d] + sum_{e in row d} HS[ssrc[e]]) + bias)
template<int OUT>
__global__ __launch_bounds__(256)
void aggregate_k(const int* __restrict__ off, const int* __restrict__ ssrc,
                 const float* __restrict__ HS, const float* __restrict__ dinv,
                 const float* __restrict__ bias, float* __restrict__ Y, int n) {
  constexpr int TPR = OUT / 4;       // lanes per row (32 or 16)
  constexpr int RPB = 256 / TPR;     // rows per block (8 or 16)
  const int lane = threadIdx.x % TPR;
  const int r    = threadIdx.x / TPR;
  const int o4   = lane * 4;
  const float4 bb = *(const float4*)&bias[o4];

  for (int d = blockIdx.x * RPB + r; d < n; d += gridDim.x * RPB) {
    int beg = off[d], end = off[d + 1];
    float4 acc = *(const float4*)&HS[(long long)d * OUT + o4];  // self-loop term
    for (int e = beg; e < end; ++e) {
      int s = ssrc[e];
      float4 v = *(const float4*)&HS[(long long)s * OUT + o4];
      acc.x += v.x; acc.y += v.y; acc.z += v.z; acc.w += v.w;
    }
    float di = dinv[d];
    float4 y;
    y.x = fmaxf(fmaf(di, acc.x, bb.x), 0.f);
    y.y = fmaxf(fmaf(di, acc.y, bb.y), 0.f);
    y.z = fmaxf(fmaf(di, acc.z, bb.z), 0.f);
    y.w = fmaxf(fmaf(di, acc.w, bb.w), 0.f);
    *(float4*)&Y[(long long)d * OUT + o4] = y;
  }
}

extern "C" void kernel_launch(void* const* d_in, const int* in_sizes, int n_in,
                              void* d_out, int out_size, void* d_ws, size_t ws_size,
                              hipStream_t stream) {
  const float* x  = (const float*)d_in[0];
  const int*   ei = (const int*)d_in[1];
  const float* W1 = (const float*)d_in[2];
  const float* b1 = (const float*)d_in[3];
  const float* W2 = (const float*)d_in[4];
  const float* b2 = (const float*)d_in[5];
  float* out = (float*)d_out;

  const int n = in_sizes[0] / IN_DIM;   // 100000
  const int E = in_sizes[1] / 2;        // 1600000

  // workspace layout (bytes)
  char* ws = (char*)d_ws;
  size_t o = 0;
  auto alloc = [&](size_t bytes) { char* p = ws + o; o = (o + bytes + 255) & ~(size_t)255; return p; };
  float* dinv   = (float*)alloc((size_t)n * 4);
  int*   off    = (int*)  alloc((size_t)(n + 1) * 4);
  int*   cursor = (int*)  alloc((size_t)n * 4);
  int*   cnt    = (int*)  alloc((size_t)n * 4);
  int*   ssrc   = (int*)  alloc((size_t)E * 4);
  float* A      = (float*)alloc((size_t)n * 128 * 4);  // HS1, then HS2
  float* B      = (float*)alloc((size_t)n * 128 * 4);  // x1 (layer-1 output)

  const int nb = (n + 255) / 256;

  // ----- CSR build (once, reused by both layers) -----
  hipMemsetAsync(cnt, 0, (size_t)n * 4, stream);
  count_deg_k<<<2048, 256, 0, stream>>>(ei, E, cnt);
  dinv_k<<<nb, 256, 0, stream>>>(cnt, dinv, n);
  scan_k<<<1, 1024, 0, stream>>>(cnt, off, cursor, n);
  fill_csr_k<<<2048, 256, 0, stream>>>(ei, E, cursor, ssrc);

  // ----- layer 1 (128 -> 128) -----
  matmul_scale_k<128><<<dim3(1024, 2), 256, 0, stream>>>(x, W1, dinv, A, n);
  aggregate_k<128><<<4096, 256, 0, stream>>>(off, ssrc, A, dinv, b1, B, n);

  // ----- layer 2 (128 -> 64) -----
  matmul_scale_k<64><<<dim3(1024, 1), 256, 0, stream>>>(B, W2, dinv, A, n);
  aggregate_k<64><<<4096, 256, 0, stream>>>(off, ssrc, A, dinv, b2, out, n);
}

// Round 3
// 562.919 us; speedup vs baseline: 7.6708x; 1.2957x over previous
//
#include <hip/hip_runtime.h>

constexpr int IN_DIM = 128;
constexpr int SCHUNK = 2048;  // elements per scan block (256 thr * 8)

// ---------- degree histogram (edges only; self-loop added analytically) ----------
__global__ void count_deg_k(const int* __restrict__ ei, int E, int* __restrict__ cnt) {
  int i = blockIdx.x * blockDim.x + threadIdx.x;
  int stride = gridDim.x * blockDim.x;
  for (; i < E; i += stride) {
    atomicAdd(&cnt[ei[E + i]], 1);
  }
}

__global__ void dinv_k(const int* __restrict__ cnt, float* __restrict__ dinv, int n) {
  int i = blockIdx.x * blockDim.x + threadIdx.x;
  if (i < n) dinv[i] = rsqrtf((float)cnt[i] + 1.0f);  // +1 self-loop
}

// ---------- hierarchical exclusive scan of cnt[0..n) ----------
// pass 1: per-block sums
__global__ __launch_bounds__(256)
void scan1_k(const int* __restrict__ cnt, int n, int* __restrict__ bsum) {
  __shared__ int sd[256];
  int base = blockIdx.x * SCHUNK + threadIdx.x * 8;
  int s = 0;
#pragma unroll
  for (int j = 0; j < 8; ++j) {
    int i = base + j;
    if (i < n) s += cnt[i];
  }
  sd[threadIdx.x] = s;
  __syncthreads();
  for (int ofs = 128; ofs > 0; ofs >>= 1) {
    if (threadIdx.x < ofs) sd[threadIdx.x] += sd[threadIdx.x + ofs];
    __syncthreads();
  }
  if (threadIdx.x == 0) bsum[blockIdx.x] = sd[0];
}

// pass 2: single block scans block sums (B <= 256)
__global__ __launch_bounds__(256)
void scan2_k(int* __restrict__ bsum, int B, int* __restrict__ off, int n) {
  __shared__ int sd[256];
  int v = (threadIdx.x < B) ? bsum[threadIdx.x] : 0;
  sd[threadIdx.x] = v;
  __syncthreads();
#pragma unroll
  for (int ofs = 1; ofs < 256; ofs <<= 1) {
    int t = (threadIdx.x >= ofs) ? sd[threadIdx.x - ofs] : 0;
    __syncthreads();
    sd[threadIdx.x] += t;
    __syncthreads();
  }
  if (threadIdx.x < B) bsum[threadIdx.x] = sd[threadIdx.x] - v;  // exclusive
  if (threadIdx.x == 255) off[n] = sd[255];                      // total == E
}

// pass 3: per-block exclusive scan + block offset -> off, cursor
__global__ __launch_bounds__(256)
void scan3_k(const int* __restrict__ cnt, int n, const int* __restrict__ bsum,
             int* __restrict__ off, int* __restrict__ cursor) {
  __shared__ int sd[256];
  int base = blockIdx.x * SCHUNK + threadIdx.x * 8;
  int v[8];
  int s = 0;
#pragma unroll
  for (int j = 0; j < 8; ++j) {
    int i = base + j;
    v[j] = (i < n) ? cnt[i] : 0;
    s += v[j];
  }
  sd[threadIdx.x] = s;
  __syncthreads();
#pragma unroll
  for (int ofs = 1; ofs < 256; ofs <<= 1) {
    int t = (threadIdx.x >= ofs) ? sd[threadIdx.x - ofs] : 0;
    __syncthreads();
    sd[threadIdx.x] += t;
    __syncthreads();
  }
  int running = bsum[blockIdx.x] + sd[threadIdx.x] - s;  // exclusive prefix
#pragma unroll
  for (int j = 0; j < 8; ++j) {
    int i = base + j;
    if (i < n) { off[i] = running; cursor[i] = running; }
    running += v[j];
  }
}

// ---------- scatter edges into CSR: sorted_src grouped by dst ----------
__global__ void fill_csr_k(const int* __restrict__ ei, int E,
                           int* __restrict__ cursor, int* __restrict__ ssrc) {
  int i = blockIdx.x * blockDim.x + threadIdx.x;
  int stride = gridDim.x * blockDim.x;
  for (; i < E; i += stride) {
    int s = ei[i];
    int d = ei[E + i];
    int pos = atomicAdd(&cursor[d], 1);
    ssrc[pos] = s;
  }
}

// ---------- matmul with dinv row-scale epilogue ----------
// HS[row][col0+o] = dinv[row] * sum_k X[row][k] * W[k][col0+o]
template<int OUT>
__global__ __launch_bounds__(256)
void matmul_scale_k(const float* __restrict__ X, const float* __restrict__ W,
                    const float* __restrict__ dinv, float* __restrict__ HS, int n) {
  constexpr int COLS = 64;
  constexpr int OG = COLS / 4;     // 16 threads per row
  constexpr int RPP = 256 / OG;    // 16 rows per pass
  __shared__ float Ws[IN_DIM * COLS];  // 32 KB
  __shared__ float XS[RPP * IN_DIM];   // 8 KB
  const int col0 = blockIdx.y * COLS;

  for (int i = threadIdx.x; i < IN_DIM * COLS; i += 256) {
    int k = i / COLS, c = i % COLS;
    Ws[i] = W[k * OUT + col0 + c];
  }

  const int og = threadIdx.x % OG;
  const int r  = threadIdx.x / OG;
  const int o4 = og * 4;

  for (int row0 = blockIdx.x * RPP; row0 < n; row0 += gridDim.x * RPP) {
    __syncthreads();  // also covers initial Ws staging
    for (int i = threadIdx.x; i < RPP * IN_DIM; i += 256) {
      int row = row0 + (i / IN_DIM);
      XS[i] = (row < n) ? X[(long long)row * IN_DIM + (i % IN_DIM)] : 0.0f;
    }
    __syncthreads();

    float4 acc = make_float4(0.f, 0.f, 0.f, 0.f);
#pragma unroll
    for (int k = 0; k < IN_DIM; k += 4) {
      float4 xv = *(const float4*)&XS[r * IN_DIM + k];
      const float* wp = &Ws[k * COLS + o4];
      float4 w0 = *(const float4*)(wp);
      float4 w1 = *(const float4*)(wp + COLS);
      float4 w2 = *(const float4*)(wp + 2 * COLS);
      float4 w3 = *(const float4*)(wp + 3 * COLS);
      acc.x = fmaf(xv.x, w0.x, fmaf(xv.y, w1.x, fmaf(xv.z, w2.x, fmaf(xv.w, w3.x, acc.x))));
      acc.y = fmaf(xv.x, w0.y, fmaf(xv.y, w1.y, fmaf(xv.z, w2.y, fmaf(xv.w, w3.y, acc.y))));
      acc.z = fmaf(xv.x, w0.z, fmaf(xv.y, w1.z, fmaf(xv.z, w2.z, fmaf(xv.w, w3.z, acc.z))));
      acc.w = fmaf(xv.x, w0.w, fmaf(xv.y, w1.w, fmaf(xv.z, w2.w, fmaf(xv.w, w3.w, acc.w))));
    }
    int row = row0 + r;
    if (row < n) {
      float s = dinv[row];
      *(float4*)&HS[(long long)row * OUT + col0 + o4] =
          make_float4(acc.x * s, acc.y * s, acc.z * s, acc.w * s);
    }
  }
}

// ---------- CSR aggregate + fused finalize ----------
// Y[d] = relu(dinv[d] * (HS[d] + sum_{e in row d} HS[ssrc[e]]) + bias)
template<int OUT>
__global__ __launch_bounds__(256)
void aggregate_k(const int* __restrict__ off, const int* __restrict__ ssrc,
                 const float* __restrict__ HS, const float* __restrict__ dinv,
                 const float* __restrict__ bias, float* __restrict__ Y, int n) {
  constexpr int TPR = OUT / 4;       // lanes per row (32 or 16)
  constexpr int RPB = 256 / TPR;     // rows per block (8 or 16)
  const int lane = threadIdx.x % TPR;
  const int r    = threadIdx.x / TPR;
  const int o4   = lane * 4;
  const float4 bb = *(const float4*)&bias[o4];

  for (int d = blockIdx.x * RPB + r; d < n; d += gridDim.x * RPB) {
    int beg = off[d], end = off[d + 1];
    float4 acc = *(const float4*)&HS[(long long)d * OUT + o4];  // self-loop term
    for (int e = beg; e < end; ++e) {
      int s = ssrc[e];
      float4 v = *(const float4*)&HS[(long long)s * OUT + o4];
      acc.x += v.x; acc.y += v.y; acc.z += v.z; acc.w += v.w;
    }
    float di = dinv[d];
    float4 y;
    y.x = fmaxf(fmaf(di, acc.x, bb.x), 0.f);
    y.y = fmaxf(fmaf(di, acc.y, bb.y), 0.f);
    y.z = fmaxf(fmaf(di, acc.z, bb.z), 0.f);
    y.w = fmaxf(fmaf(di, acc.w, bb.w), 0.f);
    *(float4*)&Y[(long long)d * OUT + o4] = y;
  }
}

extern "C" void kernel_launch(void* const* d_in, const int* in_sizes, int n_in,
                              void* d_out, int out_size, void* d_ws, size_t ws_size,
                              hipStream_t stream) {
  const float* x  = (const float*)d_in[0];
  const int*   ei = (const int*)d_in[1];
  const float* W1 = (const float*)d_in[2];
  const float* b1 = (const float*)d_in[3];
  const float* W2 = (const float*)d_in[4];
  const float* b2 = (const float*)d_in[5];
  float* out = (float*)d_out;

  const int n = in_sizes[0] / IN_DIM;   // 100000
  const int E = in_sizes[1] / 2;        // 1600000

  // workspace layout (bytes)
  char* ws = (char*)d_ws;
  size_t o = 0;
  auto alloc = [&](size_t bytes) { char* p = ws + o; o = (o + bytes + 255) & ~(size_t)255; return p; };
  float* dinv   = (float*)alloc((size_t)n * 4);
  int*   off    = (int*)  alloc((size_t)(n + 1) * 4);
  int*   cursor = (int*)  alloc((size_t)n * 4);
  int*   cnt    = (int*)  alloc((size_t)n * 4);
  int*   bsum   = (int*)  alloc((size_t)256 * 4);
  int*   ssrc   = (int*)  alloc((size_t)E * 4);
  float* A      = (float*)alloc((size_t)n * 128 * 4);  // HS1, then HS2
  float* B      = (float*)alloc((size_t)n * 128 * 4);  // x1 (layer-1 output)

  const int nb = (n + 255) / 256;
  const int nscan = (n + SCHUNK - 1) / SCHUNK;  // 49 blocks (<= 256 required)

  // ----- CSR build (once, reused by both layers) -----
  hipMemsetAsync(cnt, 0, (size_t)n * 4, stream);
  count_deg_k<<<2048, 256, 0, stream>>>(ei, E, cnt);
  dinv_k<<<nb, 256, 0, stream>>>(cnt, dinv, n);
  scan1_k<<<nscan, 256, 0, stream>>>(cnt, n, bsum);
  scan2_k<<<1, 256, 0, stream>>>(bsum, nscan, off, n);
  scan3_k<<<nscan, 256, 0, stream>>>(cnt, n, bsum, off, cursor);
  fill_csr_k<<<2048, 256, 0, stream>>>(ei, E, cursor, ssrc);

  // ----- layer 1 (128 -> 128) -----
  matmul_scale_k<128><<<dim3(1024, 2), 256, 0, stream>>>(x, W1, dinv, A, n);
  aggregate_k<128><<<4096, 256, 0, stream>>>(off, ssrc, A, dinv, b1, B, n);

  // ----- layer 2 (128 -> 64) -----
  matmul_scale_k<64><<<dim3(1024, 1), 256, 0, stream>>>(B, W2, dinv, A, n);
  aggregate_k<64><<<4096, 256, 0, stream>>>(off, ssrc, A, dinv, b2, out, n);
}